// Round 9
// baseline (579.126 us; speedup 1.0000x reference)
//
#include <hip/hip_runtime.h>

typedef unsigned short u16;
typedef unsigned int u32;
typedef __attribute__((ext_vector_type(8))) short bf16x8;
typedef __attribute__((ext_vector_type(4))) float f32x4;
typedef __attribute__((ext_vector_type(8))) unsigned short u16x8;
typedef __attribute__((ext_vector_type(4))) u32 u32x4;

#define MFMA16 __builtin_amdgcn_mfma_f32_16x16x32_bf16

__device__ __forceinline__ u16 f2bf(float f) {
  unsigned u = __float_as_uint(f);
  u += 0x7fffu + ((u >> 16) & 1u);
  return (u16)(u >> 16);
}

__device__ __forceinline__ void async16(void* lds, const void* g) {
  __builtin_amdgcn_global_load_lds(
      (const __attribute__((address_space(1))) unsigned int*)g,
      (__attribute__((address_space(3))) unsigned int*)lds, 16, 0, 0);
}

// ---------------- f32 -> bf16 conversion (vectorized, memory-bound) --------
__global__ void convert_bf16(const float* __restrict__ in, u16* __restrict__ out, int n4) {
  int i = blockIdx.x * blockDim.x + threadIdx.x;
  int st = gridDim.x * blockDim.x;
  for (; i < n4; i += st) {
    float4 f = ((const float4*)in)[i];
    ushort4 o;
    o.x = f2bf(f.x); o.y = f2bf(f.y); o.z = f2bf(f.z); o.w = f2bf(f.w);
    ((ushort4*)out)[i] = o;
  }
}

// ============ 8-phase 256x256 GEMM core (B^T, K=2048, BK=64, 8 waves) ======
// (unchanged from round 8 -- passed, ~1150 TF)
#define GEMM256_CORE(A_, B_)                                                    \
  __shared__ __align__(16) char lds[131072];                                    \
  const int tid = threadIdx.x;                                                  \
  const int lane = tid & 63, w = tid >> 6;                                      \
  const int wr = w >> 2, wc = w & 3;                                            \
  const int fr = lane & 15, fq = lane >> 4;                                     \
  const int lrA = tid >> 3, ccA = tid & 7, w8 = w << 3;                         \
  f32x4 acc[8][4] = {};                                                         \
  const u16* Abase = A_ + (size_t)tm * 2048;                                    \
  const u16* Bbase = B_ + (size_t)tn * 2048;                                    \
  auto stageA = [&](int mh, int kt, char* buf) {                                \
    _Pragma("unroll") for (int it = 0; it < 2; ++it) {                          \
      int lrt = it * 64 + lrA;                                                  \
      int row = mh * 64 + (lrt & 63) + ((lrt & 64) << 1);                       \
      const u16* src = Abase + (size_t)row * 2048 + kt + ((ccA ^ (row & 7)) << 3); \
      int lr0 = it * 64 + w8;                                                   \
      int row0 = mh * 64 + (lr0 & 63) + ((lr0 & 64) << 1);                      \
      async16(buf + row0 * 128, src);                                           \
    }                                                                           \
  };                                                                            \
  auto stageB = [&](int nh, int kt, char* buf) {                                \
    _Pragma("unroll") for (int it = 0; it < 2; ++it) {                          \
      int lrt = it * 64 + lrA;                                                  \
      int nr = ((lrt >> 5) << 6) + nh * 32 + (lrt & 31);                        \
      const u16* src = Bbase + (size_t)nr * 2048 + kt + ((ccA ^ (nr & 7)) << 3); \
      int lr0 = it * 64 + w8;                                                   \
      int nr0 = ((lr0 >> 5) << 6) + nh * 32 + (lr0 & 31);                       \
      async16(buf + 32768 + nr0 * 128, src);                                    \
    }                                                                           \
  };                                                                            \
  stageA(0, 0, lds); stageB(0, 0, lds); stageB(1, 0, lds); stageA(1, 0, lds);   \
  for (int t = 0; t < 32; ++t) {                                                \
    char* cur = lds + (t & 1) * 65536;                                          \
    char* nxt = lds + ((t + 1) & 1) * 65536;                                    \
    const int ktn = (t + 1) * 64;                                               \
    const bool more = (t + 1 < 32);                                             \
    _Pragma("unroll") for (int p = 0; p < 4; ++p) {                             \
      const int mh = p >> 1, nh = (p == 1 || p == 2) ? 1 : 0;                   \
      if (p < 3) asm volatile("s_waitcnt vmcnt(4)" ::: "memory");               \
      __builtin_amdgcn_s_barrier();                                             \
      asm volatile("" ::: "memory");                                            \
      bf16x8 af[4][2], bfr[2][2];                                               \
      _Pragma("unroll") for (int i = 0; i < 4; ++i) {                           \
        int rr = wr * 128 + mh * 64 + i * 16 + fr;                              \
        _Pragma("unroll") for (int ks = 0; ks < 2; ++ks)                        \
          af[i][ks] = *(const bf16x8*)(cur + rr * 128 +                         \
                                       (((ks * 4 + fq) ^ (rr & 7)) << 4));      \
      }                                                                         \
      _Pragma("unroll") for (int j = 0; j < 2; ++j) {                           \
        int nr = wc * 64 + nh * 32 + j * 16 + fr;                               \
        _Pragma("unroll") for (int ks = 0; ks < 2; ++ks)                        \
          bfr[j][ks] = *(const bf16x8*)(cur + 32768 + nr * 128 +                \
                                        (((ks * 4 + fq) ^ (nr & 7)) << 4));     \
      }                                                                         \
      if (more) {                                                               \
        if (p == 0) stageA(0, ktn, nxt);                                        \
        else if (p == 1) stageB(0, ktn, nxt);                                   \
        else if (p == 2) stageB(1, ktn, nxt);                                   \
        else stageA(1, ktn, nxt);                                               \
      }                                                                         \
      __builtin_amdgcn_s_setprio(1);                                            \
      _Pragma("unroll") for (int ks = 0; ks < 2; ++ks)                          \
        _Pragma("unroll") for (int i = 0; i < 4; ++i)                           \
          _Pragma("unroll") for (int j = 0; j < 2; ++j)                         \
            acc[mh * 4 + i][nh * 2 + j] = MFMA16(af[i][ks], bfr[j][ks],         \
                                                 acc[mh * 4 + i][nh * 2 + j],   \
                                                 0, 0, 0);                      \
      __builtin_amdgcn_s_setprio(0);                                            \
    }                                                                           \
  }

// qkv: A=x_bf [8192][2048], B=win_bf [6144][2048]; scatter to Q/K/V [B,H,T,D]
__global__ __launch_bounds__(512, 2) void gemm_qkv8(
    const u16* __restrict__ A, const u16* __restrict__ B,
    u16* __restrict__ Qb, u16* __restrict__ Kb, u16* __restrict__ Vb) {
  int id = blockIdx.x;                       // 768 blocks, 768%8==0
  int swz = (id & 7) * 96 + (id >> 3);       // XCD-contiguous chunks
  const int tm = (swz / 24) * 256, tn = (swz % 24) * 256;
  GEMM256_CORE(A, B)
#pragma unroll
  for (int J = 0; J < 4; ++J) {
    int n = tn + wc * 64 + J * 16 + fr;
    int which = n >> 11, h = (n >> 7) & 15, d = n & 127;
    u16* dst = which == 0 ? Qb : (which == 1 ? Kb : Vb);
#pragma unroll
    for (int I = 0; I < 8; ++I)
#pragma unroll
      for (int rr = 0; rr < 4; ++rr) {
        int m = tm + wr * 128 + I * 16 + fq * 4 + rr;
        int bb = m >> 11, tt = m & 2047;
        dst[((size_t)((bb * 16 + h) * 2048 + tt) << 7) + d] = f2bf(acc[I][J][rr]);
      }
  }
}

// out-projection: A=y_bf [8192][2048], B=wout_bf [2048][2048]; C f32 [8192][2048]
__global__ __launch_bounds__(512, 2) void gemm_out8(
    const u16* __restrict__ A, const u16* __restrict__ B, float* __restrict__ C) {
  int id = blockIdx.x;                       // 256 blocks
  int swz = (id & 7) * 32 + (id >> 3);
  const int tm = (swz / 8) * 256, tn = (swz % 8) * 256;
  GEMM256_CORE(A, B)
#pragma unroll
  for (int J = 0; J < 4; ++J) {
    int n = tn + wc * 64 + J * 16 + fr;
#pragma unroll
    for (int I = 0; I < 8; ++I)
#pragma unroll
      for (int rr = 0; rr < 4; ++rr) {
        int m = tm + wr * 128 + I * 16 + fq * 4 + rr;
        C[(size_t)m * 2048 + n] = acc[I][J][rr];
      }
  }
}

// ---------------- V -> V^T (per head): Vt[pair][d][t] ----------------------
__global__ __launch_bounds__(256) void transpose_v(const u16* __restrict__ V,
                                                   u16* __restrict__ Vt) {
  __shared__ u16 lds[64 * 72];
  const int tid = threadIdx.x;
  const int pair = blockIdx.z;
  const int t0 = blockIdx.x * 64, d0 = blockIdx.y * 64;
  const u16* Vp = V + (size_t)pair * 262144;
  u16* Vtp = Vt + (size_t)pair * 262144;
#pragma unroll
  for (int it = 0; it < 2; ++it) {
    int c = it * 256 + tid;
    int t = c >> 3, ch = c & 7;
    u16x8 tv = *(const u16x8*)&Vp[(size_t)(t0 + t) * 128 + d0 + ch * 8];
#pragma unroll
    for (int jj = 0; jj < 8; ++jj) lds[(ch * 8 + jj) * 72 + t] = tv[jj];
  }
  __syncthreads();
#pragma unroll
  for (int it = 0; it < 2; ++it) {
    int c = it * 256 + tid;
    int d = c >> 3, ct = c & 7;
    u16x8 tv = *(const u16x8*)&lds[d * 72 + ct * 8];
    *(u16x8*)&Vtp[(size_t)(d0 + d) * 2048 + t0 + ct * 8] = tv;
  }
}

// ---------------- flash attention v9: V direct from L2, singleton grid -----
// Changes vs r8 (passed, 230us): (1) V no longer staged in LDS -- PV reads
// Vt straight from global (L2-resident, 512KB/pair); halves per-tile LDS
// read traffic (was 8 waves x 32KB, now 8 x 16KB). (2) grid un-paired:
// (pair, 16 q-blocks), longest-first (qb = 15-by) -> LPT backfill replaces
// explicit pairing; LDS 32K -> up to 5 blocks/CU. (3) launch_bounds(512,4):
// VGPR cap 128, no spill (r7 lesson).
__global__ __launch_bounds__(512, 4) void attn9(
    const u16* __restrict__ Q, const u16* __restrict__ K,
    const u16* __restrict__ Vt, u16* __restrict__ Y) {
  __shared__ __align__(16) char smem[32768];
  char* lK = smem;
  char* lP = smem + 16384;
  const int tid = threadIdx.x;
  const int lane = tid & 63, w = tid >> 6;
  const int fr = lane & 15, fq = lane >> 4;
  const int pair = blockIdx.x;
  const int qb = 15 - blockIdx.y;            // longest blocks launch first
  const size_t hoff = (size_t)pair * 262144;
  const u16* Qh = Q + hoff;
  const u16* Kh = K + hoff;
  const u16* Vth = Vt + hoff;
  const int b = pair >> 4, h = pair & 15;
  const float c1 = 0.08838834764831845f * 1.4426950408889634f;
  const float THR = 11.5f;

  int ksr[2], kcc[2];
#pragma unroll
  for (int it = 0; it < 2; ++it) {
    int idx = it * 512 + tid;
    ksr[it] = idx >> 4; kcc[it] = idx & 15;   // K: row 0..63, chunk 0..15
  }

  const int q0 = qb * 128;
  const int nt = 2 * qb + 2;
  const int qw = q0 + w * 16;

  bf16x8 qf[4];
#pragma unroll
  for (int ks = 0; ks < 4; ++ks)
    qf[ks] = *(const bf16x8*)&Qh[(size_t)(qw + fr) * 128 + ks * 32 + fq * 8];

  f32x4 o[8] = {};
  float m2[4], ls[4];
#pragma unroll
  for (int r = 0; r < 4; ++r) { m2[r] = -1e30f; ls[r] = 0.f; }

  // preload K tile 0 into registers
  u32x4 kst[2];
#pragma unroll
  for (int it = 0; it < 2; ++it)
    kst[it] = *(const u32x4*)&Kh[(size_t)ksr[it] * 128 + kcc[it] * 8];

  for (int t = 0; t < nt; ++t) {
    const int kv0 = t * 64;
    // ds_write staged K tile t (swizzled)
#pragma unroll
    for (int it = 0; it < 2; ++it)
      *(u32x4*)(lK + ksr[it] * 256 + ((kcc[it] ^ (ksr[it] & 7)) << 4)) = kst[it];
    // issue next K tile loads
    if (t + 1 < nt) {
      const int nk = kv0 + 64;
#pragma unroll
      for (int it = 0; it < 2; ++it)
        kst[it] = *(const u32x4*)&Kh[(size_t)(nk + ksr[it]) * 128 + kcc[it] * 8];
    }
    __syncthreads();  // lK visible

    if (kv0 <= qw + 15) {  // wave-uniform skip of fully-masked tiles
      // QK^T: sc[j][r]: q row = qw + fq*4 + r, kv col = kv0 + j*16 + fr
      f32x4 sc[4] = {};
#pragma unroll
      for (int j = 0; j < 4; ++j) {
        int s = j * 16 + fr;
#pragma unroll
        for (int ks = 0; ks < 4; ++ks) {
          bf16x8 kf = *(const bf16x8*)(lK + s * 256 + (((ks * 32 + fq * 8) * 2) ^ ((s & 7) << 4)));
          sc[j] = MFMA16(qf[ks], kf, sc[j], 0, 0, 0);
        }
      }
      // causal mask
      if (kv0 + 64 > qw) {
        int rowb = qw + fq * 4;
#pragma unroll
        for (int j = 0; j < 4; ++j) {
          int col = kv0 + j * 16 + fr;
#pragma unroll
          for (int r = 0; r < 4; ++r)
            if (col > rowb + r) sc[j][r] = -3e38f;
        }
      }
      // speculative defer-max softmax (r8-proven)
      float lmax[4];
      bool trip = false;
#pragma unroll
      for (int r = 0; r < 4; ++r) {
        lmax[r] = fmaxf(fmaxf(sc[0][r], sc[1][r]), fmaxf(sc[2][r], sc[3][r]));
        trip = trip || (lmax[r] * c1 > m2[r] + THR);
      }
      if (__any(trip)) {
#pragma unroll
        for (int r = 0; r < 4; ++r) {
          float v = lmax[r];
          v = fmaxf(v, __shfl_xor(v, 1));
          v = fmaxf(v, __shfl_xor(v, 2));
          v = fmaxf(v, __shfl_xor(v, 4));
          v = fmaxf(v, __shfl_xor(v, 8));
          v *= c1;
          float mn = fmaxf(m2[r], v);
          float corr = __builtin_amdgcn_exp2f(m2[r] - mn);
          m2[r] = mn;
          ls[r] *= corr;
#pragma unroll
          for (int n = 0; n < 8; ++n) o[n][r] *= corr;
        }
      }
#pragma unroll
      for (int r = 0; r < 4; ++r) {
        int prow = w * 16 + fq * 4 + r;
        float rs = 0.f;
#pragma unroll
        for (int j = 0; j < 4; ++j) {
          float p = __builtin_amdgcn_exp2f(sc[j][r] * c1 - m2[r]);
          rs += p;
          *(u16*)(lP + prow * 128 + (((j * 16 + fr) * 2) ^ ((prow & 7) << 4))) = f2bf(p);
        }
        ls[r] += rs;
      }
      // PV: o[n] += P(16x64) * V(64x128); V direct from global (L2),
      // 1-deep manual prefetch across n (all indices static -- rule #20)
      bf16x8 pf[2];
      {
        int prow = w * 16 + fr;
#pragma unroll
        for (int k2 = 0; k2 < 2; ++k2)
          pf[k2] = *(const bf16x8*)(lP + prow * 128 + ((k2 * 64 + fq * 16) ^ ((prow & 7) << 4)));
      }
      const u16* Vrow = Vth + kv0 + fq * 8;
      bf16x8 va0, va1, vb0, vb1;
      va0 = *(const bf16x8*)&Vrow[(size_t)(0 * 16 + fr) * 2048];
      va1 = *(const bf16x8*)&Vrow[(size_t)(0 * 16 + fr) * 2048 + 32];
#pragma unroll
      for (int n = 0; n < 8; ++n) {
        if (n < 7) {
          vb0 = *(const bf16x8*)&Vrow[(size_t)((n + 1) * 16 + fr) * 2048];
          vb1 = *(const bf16x8*)&Vrow[(size_t)((n + 1) * 16 + fr) * 2048 + 32];
        }
        o[n] = MFMA16(pf[0], va0, o[n], 0, 0, 0);
        o[n] = MFMA16(pf[1], va1, o[n], 0, 0, 0);
        va0 = vb0; va1 = vb1;
      }
    }
    __syncthreads();  // all QK^T/P reads done before next tile's lK write
  }

  // epilogue: reduce per-lane partial ls, normalize, write y [B,T,H*D] bf16
  float inv[4];
#pragma unroll
  for (int r = 0; r < 4; ++r) {
    float s = ls[r];
    s += __shfl_xor(s, 1);
    s += __shfl_xor(s, 2);
    s += __shfl_xor(s, 4);
    s += __shfl_xor(s, 8);
    inv[r] = 1.f / s;
  }
#pragma unroll
  for (int n = 0; n < 8; ++n)
#pragma unroll
    for (int r = 0; r < 4; ++r) {
      int tt = qw + fq * 4 + r;
      Y[((size_t)(b * 2048 + tt) * 2048) + h * 128 + n * 16 + fr] = f2bf(o[n][r] * inv[r]);
    }
}

// ---------------------------------------------------------------------------
extern "C" void kernel_launch(void* const* d_in, const int* in_sizes, int n_in,
                              void* d_out, int out_size, void* d_ws, size_t ws_size,
                              hipStream_t stream) {
  const float* x = (const float*)d_in[0];
  const float* Win = (const float*)d_in[1];
  const float* Wout = (const float*)d_in[2];
  float* out = (float*)d_out;
  char* ws = (char*)d_ws;

  u16* x_bf   = (u16*)(ws);                  // 33554432 B (reused as Vt after gemm)
  u16* win_bf = (u16*)(ws + 33554432);       // 25165824 B
  u16* wout_bf= (u16*)(ws + 58720256);       //  8388608 B
  u16* Qb     = (u16*)(ws + 67108864);       // 33554432 B
  u16* Kb     = (u16*)(ws + 100663296);      // 33554432 B
  u16* Vb     = (u16*)(ws + 134217728);      // 33554432 B
  u16* y_bf   = (u16*)(ws + 167772160);      // 33554432 B  (total 192 MiB)
  u16* Vtb    = x_bf;                        // x_bf dead after gemm_qkv8

  convert_bf16<<<2048, 256, 0, stream>>>(x, x_bf, 16777216 / 4);
  convert_bf16<<<2048, 256, 0, stream>>>(Win, win_bf, 12582912 / 4);
  convert_bf16<<<1024, 256, 0, stream>>>(Wout, wout_bf, 4194304 / 4);

  gemm_qkv8<<<768, 512, 0, stream>>>(x_bf, win_bf, Qb, Kb, Vb);
  transpose_v<<<dim3(32, 2, 64), 256, 0, stream>>>(Vb, Vtb);
  attn9<<<dim3(64, 16), 512, 0, stream>>>(Qb, Kb, Vtb, y_bf);
  gemm_out8<<<256, 512, 0, stream>>>(y_bf, wout_bf, out);
}

// Round 11
// 539.510 us; speedup vs baseline: 1.0734x; 1.0734x over previous
//
#include <hip/hip_runtime.h>

typedef unsigned short u16;
typedef unsigned int u32;
typedef __attribute__((ext_vector_type(8))) short bf16x8;
typedef __attribute__((ext_vector_type(4))) float f32x4;
typedef __attribute__((ext_vector_type(8))) unsigned short u16x8;
typedef __attribute__((ext_vector_type(4))) u32 u32x4;

#define MFMA16 __builtin_amdgcn_mfma_f32_16x16x32_bf16

__device__ __forceinline__ u16 f2bf(float f) {
  unsigned u = __float_as_uint(f);
  u += 0x7fffu + ((u >> 16) & 1u);
  return (u16)(u >> 16);
}

__device__ __forceinline__ void async16(void* lds, const void* g) {
  __builtin_amdgcn_global_load_lds(
      (const __attribute__((address_space(1))) unsigned int*)g,
      (__attribute__((address_space(3))) unsigned int*)lds, 16, 0, 0);
}

// ---------------- f32 -> bf16 conversion (vectorized, memory-bound) --------
__global__ void convert_bf16(const float* __restrict__ in, u16* __restrict__ out, int n4) {
  int i = blockIdx.x * blockDim.x + threadIdx.x;
  int st = gridDim.x * blockDim.x;
  for (; i < n4; i += st) {
    float4 f = ((const float4*)in)[i];
    ushort4 o;
    o.x = f2bf(f.x); o.y = f2bf(f.y); o.z = f2bf(f.z); o.w = f2bf(f.w);
    ((ushort4*)out)[i] = o;
  }
}

// ============ 8-phase 256x256 GEMM core (r8 ordering, race-fixed tail) =====
// Per phase: vmcnt(N) -> s_barrier -> ds_read(cur) -> stage half(nxt) ->
// setprio(1) MFMA setprio(0). Reads come AFTER the barrier that follows every
// wave's vmcnt (r10 lesson: reads before that barrier race with other waves'
// in-flight global_load_lds). Mid-loop waits: vmcnt(4) at p0..p2 (same as r8,
// proven). FINAL tile (no stages issued): p1 -> vmcnt(2) so Bh1 (staged
// t30.p2) is landed; p2 -> vmcnt(0) so Ah1 (t30.p3) is landed -- closes r8's
// latent epilogue race that timing had masked.
#define GEMM256_CORE(A_, B_)                                                    \
  __shared__ __align__(16) char lds[131072];                                    \
  const int tid = threadIdx.x;                                                  \
  const int lane = tid & 63, w = tid >> 6;                                      \
  const int wr = w >> 2, wc = w & 3;                                            \
  const int fr = lane & 15, fq = lane >> 4;                                     \
  const int lrA = tid >> 3, ccA = tid & 7, w8 = w << 3;                         \
  f32x4 acc[8][4] = {};                                                         \
  const u16* Abase = A_ + (size_t)tm * 2048;                                    \
  const u16* Bbase = B_ + (size_t)tn * 2048;                                    \
  auto stageA = [&](int mh, int kt, char* buf) {                                \
    _Pragma("unroll") for (int it = 0; it < 2; ++it) {                          \
      int lrt = it * 64 + lrA;                                                  \
      int row = mh * 64 + (lrt & 63) + ((lrt & 64) << 1);                       \
      const u16* src = Abase + (size_t)row * 2048 + kt + ((ccA ^ (row & 7)) << 3); \
      int lr0 = it * 64 + w8;                                                   \
      int row0 = mh * 64 + (lr0 & 63) + ((lr0 & 64) << 1);                      \
      async16(buf + row0 * 128, src);                                           \
    }                                                                           \
  };                                                                            \
  auto stageB = [&](int nh, int kt, char* buf) {                                \
    _Pragma("unroll") for (int it = 0; it < 2; ++it) {                          \
      int lrt = it * 64 + lrA;                                                  \
      int nr = ((lrt >> 5) << 6) + nh * 32 + (lrt & 31);                        \
      const u16* src = Bbase + (size_t)nr * 2048 + kt + ((ccA ^ (nr & 7)) << 3); \
      int lr0 = it * 64 + w8;                                                   \
      int nr0 = ((lr0 >> 5) << 6) + nh * 32 + (lr0 & 31);                       \
      async16(buf + 32768 + nr0 * 128, src);                                    \
    }                                                                           \
  };                                                                            \
  stageA(0, 0, lds); stageB(0, 0, lds); stageB(1, 0, lds); stageA(1, 0, lds);   \
  for (int t = 0; t < 32; ++t) {                                                \
    char* cur = lds + (t & 1) * 65536;                                          \
    char* nxt = lds + ((t + 1) & 1) * 65536;                                    \
    const int ktn = (t + 1) * 64;                                               \
    const bool more = (t + 1 < 32);                                             \
    _Pragma("unroll") for (int p = 0; p < 4; ++p) {                             \
      const int mh = p >> 1, nh = (p == 1 || p == 2) ? 1 : 0;                   \
      if (p == 0) {                                                             \
        asm volatile("s_waitcnt vmcnt(4)" ::: "memory");                        \
      } else if (p == 1) {                                                      \
        if (more) asm volatile("s_waitcnt vmcnt(4)" ::: "memory");              \
        else      asm volatile("s_waitcnt vmcnt(2)" ::: "memory");              \
      } else if (p == 2) {                                                      \
        if (more) asm volatile("s_waitcnt vmcnt(4)" ::: "memory");              \
        else      asm volatile("s_waitcnt vmcnt(0)" ::: "memory");              \
      }                                                                         \
      __builtin_amdgcn_s_barrier();                                             \
      asm volatile("" ::: "memory");                                            \
      bf16x8 af[4][2], bfr[2][2];                                               \
      _Pragma("unroll") for (int i = 0; i < 4; ++i) {                           \
        int rr = wr * 128 + mh * 64 + i * 16 + fr;                              \
        _Pragma("unroll") for (int ks = 0; ks < 2; ++ks)                        \
          af[i][ks] = *(const bf16x8*)(cur + rr * 128 +                         \
                                       (((ks * 4 + fq) ^ (rr & 7)) << 4));      \
      }                                                                         \
      _Pragma("unroll") for (int j = 0; j < 2; ++j) {                           \
        int nr = wc * 64 + nh * 32 + j * 16 + fr;                               \
        _Pragma("unroll") for (int ks = 0; ks < 2; ++ks)                        \
          bfr[j][ks] = *(const bf16x8*)(cur + 32768 + nr * 128 +                \
                                        (((ks * 4 + fq) ^ (nr & 7)) << 4));     \
      }                                                                         \
      if (more) {                                                               \
        if (p == 0) stageA(0, ktn, nxt);                                        \
        else if (p == 1) stageB(0, ktn, nxt);                                   \
        else if (p == 2) stageB(1, ktn, nxt);                                   \
        else stageA(1, ktn, nxt);                                               \
      }                                                                         \
      __builtin_amdgcn_s_setprio(1);                                            \
      _Pragma("unroll") for (int ks = 0; ks < 2; ++ks)                          \
        _Pragma("unroll") for (int i = 0; i < 4; ++i)                           \
          _Pragma("unroll") for (int j = 0; j < 2; ++j)                         \
            acc[mh * 4 + i][nh * 2 + j] = MFMA16(af[i][ks], bfr[j][ks],         \
                                                 acc[mh * 4 + i][nh * 2 + j],   \
                                                 0, 0, 0);                      \
      __builtin_amdgcn_s_setprio(0);                                            \
    }                                                                           \
  }

// qkv: A=x_bf [8192][2048], B=win_bf [6144][2048]; scatter to Q/K/V [B,H,T,D]
__global__ __launch_bounds__(512, 2) void gemm_qkv8(
    const u16* __restrict__ A, const u16* __restrict__ B,
    u16* __restrict__ Qb, u16* __restrict__ Kb, u16* __restrict__ Vb) {
  int id = blockIdx.x;                       // 768 blocks, 768%8==0
  int swz = (id & 7) * 96 + (id >> 3);       // XCD-contiguous chunks
  const int tm = (swz / 24) * 256, tn = (swz % 24) * 256;
  GEMM256_CORE(A, B)
#pragma unroll
  for (int J = 0; J < 4; ++J) {
    int n = tn + wc * 64 + J * 16 + fr;
    int which = n >> 11, h = (n >> 7) & 15, d = n & 127;
    u16* dst = which == 0 ? Qb : (which == 1 ? Kb : Vb);
#pragma unroll
    for (int I = 0; I < 8; ++I)
#pragma unroll
      for (int rr = 0; rr < 4; ++rr) {
        int m = tm + wr * 128 + I * 16 + fq * 4 + rr;
        int bb = m >> 11, tt = m & 2047;
        dst[((size_t)((bb * 16 + h) * 2048 + tt) << 7) + d] = f2bf(acc[I][J][rr]);
      }
  }
}

// out-projection: A=y_bf [8192][2048], B=wout_bf [2048][2048]; C f32 [8192][2048]
__global__ __launch_bounds__(512, 2) void gemm_out8(
    const u16* __restrict__ A, const u16* __restrict__ B, float* __restrict__ C) {
  int id = blockIdx.x;                       // 256 blocks
  int swz = (id & 7) * 32 + (id >> 3);
  const int tm = (swz / 8) * 256, tn = (swz % 8) * 256;
  GEMM256_CORE(A, B)
#pragma unroll
  for (int J = 0; J < 4; ++J) {
    int n = tn + wc * 64 + J * 16 + fr;
#pragma unroll
    for (int I = 0; I < 8; ++I)
#pragma unroll
      for (int rr = 0; rr < 4; ++rr) {
        int m = tm + wr * 128 + I * 16 + fq * 4 + rr;
        C[(size_t)m * 2048 + n] = acc[I][J][rr];
      }
  }
}

// ---------------- V -> V^T (per head): Vt[pair][d][t] ----------------------
__global__ __launch_bounds__(256) void transpose_v(const u16* __restrict__ V,
                                                   u16* __restrict__ Vt) {
  __shared__ u16 lds[64 * 72];
  const int tid = threadIdx.x;
  const int pair = blockIdx.z;
  const int t0 = blockIdx.x * 64, d0 = blockIdx.y * 64;
  const u16* Vp = V + (size_t)pair * 262144;
  u16* Vtp = Vt + (size_t)pair * 262144;
#pragma unroll
  for (int it = 0; it < 2; ++it) {
    int c = it * 256 + tid;
    int t = c >> 3, ch = c & 7;
    u16x8 tv = *(const u16x8*)&Vp[(size_t)(t0 + t) * 128 + d0 + ch * 8];
#pragma unroll
    for (int jj = 0; jj < 8; ++jj) lds[(ch * 8 + jj) * 72 + t] = tv[jj];
  }
  __syncthreads();
#pragma unroll
  for (int it = 0; it < 2; ++it) {
    int c = it * 256 + tid;
    int d = c >> 3, ct = c & 7;
    u16x8 tv = *(const u16x8*)&lds[d * 72 + ct * 8];
    *(u16x8*)&Vtp[(size_t)(d0 + d) * 2048 + t0 + ct * 8] = tv;
  }
}

// ---------------- flash attention: r8's attn8 verbatim (230us proven) ------
__global__ __launch_bounds__(512, 4) void attn8(
    const u16* __restrict__ Q, const u16* __restrict__ K,
    const u16* __restrict__ Vt, u16* __restrict__ Y) {
  __shared__ __align__(16) char smem[49152];
  char* lK = smem;
  char* lV = smem + 16384;
  char* lP = smem + 32768;
  const int tid = threadIdx.x;
  const int lane = tid & 63, w = tid >> 6;
  const int fr = lane & 15, fq = lane >> 4;
  const int pair = blockIdx.x, by = blockIdx.y;
  const size_t hoff = (size_t)pair * 262144;
  const u16* Qh = Q + hoff;
  const u16* Kh = K + hoff;
  const u16* Vth = Vt + hoff;
  const int b = pair >> 4, h = pair & 15;
  const float c1 = 0.08838834764831845f * 1.4426950408889634f;
  const float THR = 11.5f;

  int ksr[2], kcc[2], vdr[2], vcc[2];
#pragma unroll
  for (int it = 0; it < 2; ++it) {
    int idx = it * 512 + tid;
    ksr[it] = idx >> 4; kcc[it] = idx & 15;
    vdr[it] = idx >> 3; vcc[it] = idx & 7;
  }

  for (int phase = 0; phase < 2; ++phase) {
    const int qb = phase ? 15 - by : by;
    const int q0 = qb * 128;
    const int nt = 2 * qb + 2;
    const int qw = q0 + w * 16;

    bf16x8 qf[4];
#pragma unroll
    for (int ks = 0; ks < 4; ++ks)
      qf[ks] = *(const bf16x8*)&Qh[(size_t)(qw + fr) * 128 + ks * 32 + fq * 8];

    f32x4 o[8] = {};
    float m2[4], ls[4];
#pragma unroll
    for (int r = 0; r < 4; ++r) { m2[r] = -1e30f; ls[r] = 0.f; }

    u32x4 kst[2], vst[2];
#pragma unroll
    for (int it = 0; it < 2; ++it) {
      kst[it] = *(const u32x4*)&Kh[(size_t)ksr[it] * 128 + kcc[it] * 8];
      vst[it] = *(const u32x4*)&Vth[(size_t)vdr[it] * 2048 + vcc[it] * 8];
    }

    for (int t = 0; t < nt; ++t) {
      const int kv0 = t * 64;
#pragma unroll
      for (int it = 0; it < 2; ++it) {
        *(u32x4*)(lK + ksr[it] * 256 + ((kcc[it] ^ (ksr[it] & 7)) << 4)) = kst[it];
        *(u32x4*)(lV + vdr[it] * 128 + ((vcc[it] ^ (vdr[it] & 7)) << 4)) = vst[it];
      }
      if (t + 1 < nt) {
        const int nk = kv0 + 64;
#pragma unroll
        for (int it = 0; it < 2; ++it) {
          kst[it] = *(const u32x4*)&Kh[(size_t)(nk + ksr[it]) * 128 + kcc[it] * 8];
          vst[it] = *(const u32x4*)&Vth[(size_t)vdr[it] * 2048 + nk + vcc[it] * 8];
        }
      }
      __syncthreads();

      if (kv0 <= qw + 15) {
        f32x4 sc[4] = {};
#pragma unroll
        for (int j = 0; j < 4; ++j) {
          int s = j * 16 + fr;
#pragma unroll
          for (int ks = 0; ks < 4; ++ks) {
            bf16x8 kf = *(const bf16x8*)(lK + s * 256 + (((ks * 32 + fq * 8) * 2) ^ ((s & 7) << 4)));
            sc[j] = MFMA16(qf[ks], kf, sc[j], 0, 0, 0);
          }
        }
        if (kv0 + 64 > qw) {
          int rowb = qw + fq * 4;
#pragma unroll
          for (int j = 0; j < 4; ++j) {
            int col = kv0 + j * 16 + fr;
#pragma unroll
            for (int r = 0; r < 4; ++r)
              if (col > rowb + r) sc[j][r] = -3e38f;
          }
        }
        float lmax[4];
        bool trip = false;
#pragma unroll
        for (int r = 0; r < 4; ++r) {
          lmax[r] = fmaxf(fmaxf(sc[0][r], sc[1][r]), fmaxf(sc[2][r], sc[3][r]));
          trip = trip || (lmax[r] * c1 > m2[r] + THR);
        }
        if (__any(trip)) {
#pragma unroll
          for (int r = 0; r < 4; ++r) {
            float v = lmax[r];
            v = fmaxf(v, __shfl_xor(v, 1));
            v = fmaxf(v, __shfl_xor(v, 2));
            v = fmaxf(v, __shfl_xor(v, 4));
            v = fmaxf(v, __shfl_xor(v, 8));
            v *= c1;
            float mn = fmaxf(m2[r], v);
            float corr = __builtin_amdgcn_exp2f(m2[r] - mn);
            m2[r] = mn;
            ls[r] *= corr;
#pragma unroll
            for (int n = 0; n < 8; ++n) o[n][r] *= corr;
          }
        }
#pragma unroll
        for (int r = 0; r < 4; ++r) {
          int prow = w * 16 + fq * 4 + r;
          float rs = 0.f;
#pragma unroll
          for (int j = 0; j < 4; ++j) {
            float p = __builtin_amdgcn_exp2f(sc[j][r] * c1 - m2[r]);
            rs += p;
            *(u16*)(lP + prow * 128 + (((j * 16 + fr) * 2) ^ ((prow & 7) << 4))) = f2bf(p);
          }
          ls[r] += rs;
        }
        bf16x8 pf[2];
        {
          int prow = w * 16 + fr;
#pragma unroll
          for (int k2 = 0; k2 < 2; ++k2)
            pf[k2] = *(const bf16x8*)(lP + prow * 128 + ((k2 * 64 + fq * 16) ^ ((prow & 7) << 4)));
        }
#pragma unroll
        for (int n = 0; n < 8; ++n) {
          int d = n * 16 + fr;
#pragma unroll
          for (int k2 = 0; k2 < 2; ++k2) {
            bf16x8 vf = *(const bf16x8*)(lV + d * 128 + ((k2 * 64 + fq * 16) ^ ((d & 7) << 4)));
            o[n] = MFMA16(pf[k2], vf, o[n], 0, 0, 0);
          }
        }
      }
      __syncthreads();
    }

    float inv[4];
#pragma unroll
    for (int r = 0; r < 4; ++r) {
      float s = ls[r];
      s += __shfl_xor(s, 1);
      s += __shfl_xor(s, 2);
      s += __shfl_xor(s, 4);
      s += __shfl_xor(s, 8);
      inv[r] = 1.f / s;
    }
#pragma unroll
    for (int n = 0; n < 8; ++n)
#pragma unroll
      for (int r = 0; r < 4; ++r) {
        int tt = qw + fq * 4 + r;
        Y[((size_t)(b * 2048 + tt) * 2048) + h * 128 + n * 16 + fr] = f2bf(o[n][r] * inv[r]);
      }
  }
}

// ---------------------------------------------------------------------------
extern "C" void kernel_launch(void* const* d_in, const int* in_sizes, int n_in,
                              void* d_out, int out_size, void* d_ws, size_t ws_size,
                              hipStream_t stream) {
  const float* x = (const float*)d_in[0];
  const float* Win = (const float*)d_in[1];
  const float* Wout = (const float*)d_in[2];
  float* out = (float*)d_out;
  char* ws = (char*)d_ws;

  u16* x_bf   = (u16*)(ws);                  // 33554432 B (reused as Vt after gemm)
  u16* win_bf = (u16*)(ws + 33554432);       // 25165824 B
  u16* wout_bf= (u16*)(ws + 58720256);       //  8388608 B
  u16* Qb     = (u16*)(ws + 67108864);       // 33554432 B
  u16* Kb     = (u16*)(ws + 100663296);      // 33554432 B
  u16* Vb     = (u16*)(ws + 134217728);      // 33554432 B
  u16* y_bf   = (u16*)(ws + 167772160);      // 33554432 B  (total 192 MiB)
  u16* Vtb    = x_bf;                        // x_bf dead after gemm_qkv8

  convert_bf16<<<2048, 256, 0, stream>>>(x, x_bf, 16777216 / 4);
  convert_bf16<<<2048, 256, 0, stream>>>(Win, win_bf, 12582912 / 4);
  convert_bf16<<<1024, 256, 0, stream>>>(Wout, wout_bf, 4194304 / 4);

  gemm_qkv8<<<768, 512, 0, stream>>>(x_bf, win_bf, Qb, Kb, Vb);
  transpose_v<<<dim3(32, 2, 64), 256, 0, stream>>>(Vb, Vtb);
  attn8<<<dim3(64, 8), 512, 0, stream>>>(Qb, Kb, Vtb, y_bf);
  gemm_out8<<<256, 512, 0, stream>>>(y_bf, wout_bf, out);
}

// Round 12
// 504.338 us; speedup vs baseline: 1.1483x; 1.0697x over previous
//
#include <hip/hip_runtime.h>

typedef unsigned short u16;
typedef unsigned int u32;
typedef __attribute__((ext_vector_type(8))) short bf16x8;
typedef __attribute__((ext_vector_type(4))) float f32x4;
typedef __attribute__((ext_vector_type(8))) unsigned short u16x8;
typedef __attribute__((ext_vector_type(4))) unsigned short u16x4;
typedef __attribute__((ext_vector_type(4))) u32 u32x4;

#define MFMA16 __builtin_amdgcn_mfma_f32_16x16x32_bf16

__device__ __forceinline__ u16 f2bf(float f) {
  unsigned u = __float_as_uint(f);
  u += 0x7fffu + ((u >> 16) & 1u);
  return (u16)(u >> 16);
}

__device__ __forceinline__ void async16(void* lds, const void* g) {
  __builtin_amdgcn_global_load_lds(
      (const __attribute__((address_space(1))) unsigned int*)g,
      (__attribute__((address_space(3))) unsigned int*)lds, 16, 0, 0);
}

// ---------------- f32 -> bf16 conversion (vectorized, memory-bound) --------
__global__ void convert_bf16(const float* __restrict__ in, u16* __restrict__ out, int n4) {
  int i = blockIdx.x * blockDim.x + threadIdx.x;
  int st = gridDim.x * blockDim.x;
  for (; i < n4; i += st) {
    float4 f = ((const float4*)in)[i];
    ushort4 o;
    o.x = f2bf(f.x); o.y = f2bf(f.y); o.z = f2bf(f.z); o.w = f2bf(f.w);
    ((ushort4*)out)[i] = o;
  }
}

// ============ 256x256 GEMM core, 2-window schedule (B^T, K=2048, BK=64) ====
// Per tile: vmcnt(2) -> barrier   [publishes Ah0,Bh0,Bh1: oldest 6 of 8]
//   W0: ds_read A-half0 + ALL B (16 b128); stage Ah0,Bh0(t+1); 32 MFMA
//       (quadrants (0,0),(0,1))
//   vmcnt(4) -> barrier           [outstanding = Ah1(t)x2 + W0 stages x4 = 6;
//                                  wait 4 => Ah1 landed]
//   W1: ds_read A-half1 only (B reused in regs); stage Bh1,Ah1(t+1); 32 MFMA
// Queue order [Ah0,Bh0,Bh1,Ah1] per wave makes each count exact. Never drains
// mid-loop; final tile waits vmcnt(0) at mid (no stages issued). WAR on nxt:
// regions last read in tile t-1, all waves past the t-start barrier.
#define GEMM256_CORE(A_, B_)                                                    \
  __shared__ __align__(16) char lds[131072];                                    \
  const int tid = threadIdx.x;                                                  \
  const int lane = tid & 63, w = tid >> 6;                                      \
  const int wr = w >> 2, wc = w & 3;                                            \
  const int fr = lane & 15, fq = lane >> 4;                                     \
  const int lrA = tid >> 3, ccA = tid & 7, w8 = w << 3;                         \
  f32x4 acc[8][4] = {};                                                         \
  const u16* Abase = A_ + (size_t)tm * 2048;                                    \
  const u16* Bbase = B_ + (size_t)tn * 2048;                                    \
  auto stageA = [&](int mh, int kt, char* buf) {                                \
    _Pragma("unroll") for (int it = 0; it < 2; ++it) {                          \
      int lrt = it * 64 + lrA;                                                  \
      int row = mh * 64 + (lrt & 63) + ((lrt & 64) << 1);                       \
      const u16* src = Abase + (size_t)row * 2048 + kt + ((ccA ^ (row & 7)) << 3); \
      int lr0 = it * 64 + w8;                                                   \
      int row0 = mh * 64 + (lr0 & 63) + ((lr0 & 64) << 1);                      \
      async16(buf + row0 * 128, src);                                           \
    }                                                                           \
  };                                                                            \
  auto stageB = [&](int nh, int kt, char* buf) {                                \
    _Pragma("unroll") for (int it = 0; it < 2; ++it) {                          \
      int lrt = it * 64 + lrA;                                                  \
      int nr = ((lrt >> 5) << 6) + nh * 32 + (lrt & 31);                        \
      const u16* src = Bbase + (size_t)nr * 2048 + kt + ((ccA ^ (nr & 7)) << 3); \
      int lr0 = it * 64 + w8;                                                   \
      int nr0 = ((lr0 >> 5) << 6) + nh * 32 + (lr0 & 31);                       \
      async16(buf + 32768 + nr0 * 128, src);                                    \
    }                                                                           \
  };                                                                            \
  stageA(0, 0, lds); stageB(0, 0, lds); stageB(1, 0, lds); stageA(1, 0, lds);   \
  for (int t = 0; t < 32; ++t) {                                                \
    char* cur = lds + (t & 1) * 65536;                                          \
    char* nxt = lds + ((t + 1) & 1) * 65536;                                    \
    const int ktn = (t + 1) * 64;                                               \
    const bool more = (t + 1 < 32);                                             \
    /* ---- window 0 ---- */                                                    \
    asm volatile("s_waitcnt vmcnt(2)" ::: "memory");                            \
    __builtin_amdgcn_s_barrier();                                               \
    asm volatile("" ::: "memory");                                              \
    bf16x8 af[4][2], bfr[4][2];                                                 \
    _Pragma("unroll") for (int i = 0; i < 4; ++i) {                             \
      int rr = wr * 128 + i * 16 + fr;                                          \
      _Pragma("unroll") for (int ks = 0; ks < 2; ++ks)                          \
        af[i][ks] = *(const bf16x8*)(cur + rr * 128 +                           \
                                     (((ks * 4 + fq) ^ (rr & 7)) << 4));        \
    }                                                                           \
    _Pragma("unroll") for (int j = 0; j < 4; ++j) {                             \
      int nr = wc * 64 + j * 16 + fr;                                           \
      _Pragma("unroll") for (int ks = 0; ks < 2; ++ks)                          \
        bfr[j][ks] = *(const bf16x8*)(cur + 32768 + nr * 128 +                  \
                                      (((ks * 4 + fq) ^ (nr & 7)) << 4));       \
    }                                                                           \
    if (more) { stageA(0, ktn, nxt); stageB(0, ktn, nxt); }                     \
    __builtin_amdgcn_s_setprio(1);                                              \
    _Pragma("unroll") for (int ks = 0; ks < 2; ++ks)                            \
      _Pragma("unroll") for (int i = 0; i < 4; ++i)                             \
        _Pragma("unroll") for (int j = 0; j < 4; ++j)                           \
          acc[i][j] = MFMA16(af[i][ks], bfr[j][ks], acc[i][j], 0, 0, 0);        \
    __builtin_amdgcn_s_setprio(0);                                              \
    /* ---- window 1 ---- */                                                    \
    if (more) asm volatile("s_waitcnt vmcnt(4)" ::: "memory");                  \
    else      asm volatile("s_waitcnt vmcnt(0)" ::: "memory");                  \
    __builtin_amdgcn_s_barrier();                                               \
    asm volatile("" ::: "memory");                                              \
    bf16x8 ag[4][2];                                                            \
    _Pragma("unroll") for (int i = 0; i < 4; ++i) {                             \
      int rr = wr * 128 + 64 + i * 16 + fr;                                     \
      _Pragma("unroll") for (int ks = 0; ks < 2; ++ks)                          \
        ag[i][ks] = *(const bf16x8*)(cur + rr * 128 +                           \
                                     (((ks * 4 + fq) ^ (rr & 7)) << 4));        \
    }                                                                           \
    if (more) { stageB(1, ktn, nxt); stageA(1, ktn, nxt); }                     \
    __builtin_amdgcn_s_setprio(1);                                              \
    _Pragma("unroll") for (int ks = 0; ks < 2; ++ks)                            \
      _Pragma("unroll") for (int i = 0; i < 4; ++i)                             \
        _Pragma("unroll") for (int j = 0; j < 4; ++j)                           \
          acc[4 + i][j] = MFMA16(ag[i][ks], bfr[j][ks], acc[4 + i][j], 0, 0, 0);\
    __builtin_amdgcn_s_setprio(0);                                              \
  }

// qkv: A=x_bf [8192][2048], B=win_bf [6144][2048].
// Q,K -> [B,H,T,D]; V -> DIRECTLY transposed Vt[pair][d][t] (transpose fused:
// 4 t-consecutive accs packed per 8B store; a wave's 128-row span never
// crosses a batch boundary since 2048%128==0).
__global__ __launch_bounds__(512, 2) void gemm_qkv8(
    const u16* __restrict__ A, const u16* __restrict__ B,
    u16* __restrict__ Qb, u16* __restrict__ Kb, u16* __restrict__ Vtb) {
  int id = blockIdx.x;                       // 768 blocks, 768%8==0
  int swz = (id & 7) * 96 + (id >> 3);       // XCD-contiguous chunks
  const int tm = (swz / 24) * 256, tn = (swz % 24) * 256;
  GEMM256_CORE(A, B)
#pragma unroll
  for (int J = 0; J < 4; ++J) {
    int n = tn + wc * 64 + J * 16 + fr;
    int which = n >> 11, h = (n >> 7) & 15, d = n & 127;
    if (which < 2) {
      u16* dst = which == 0 ? Qb : Kb;
#pragma unroll
      for (int I = 0; I < 8; ++I)
#pragma unroll
        for (int rr = 0; rr < 4; ++rr) {
          int m = tm + wr * 128 + I * 16 + fq * 4 + rr;
          int bb = m >> 11, tt = m & 2047;
          dst[((size_t)((bb * 16 + h) * 2048 + tt) << 7) + d] = f2bf(acc[I][J][rr]);
        }
    } else {  // V: write transposed, Vt[(bb*16+h)][d][t]
#pragma unroll
      for (int I = 0; I < 8; ++I) {
        int m0 = tm + wr * 128 + I * 16 + fq * 4;
        int bb = m0 >> 11, tt0 = m0 & 2047;
        u16x4 pk;
#pragma unroll
        for (int rr = 0; rr < 4; ++rr) pk[rr] = f2bf(acc[I][J][rr]);
        *(u16x4*)&Vtb[(size_t)(bb * 16 + h) * 262144 + (size_t)d * 2048 + tt0] = pk;
      }
    }
  }
}

// out-projection: A=y_bf [8192][2048], B=wout_bf [2048][2048]; C f32 [8192][2048]
__global__ __launch_bounds__(512, 2) void gemm_out8(
    const u16* __restrict__ A, const u16* __restrict__ B, float* __restrict__ C) {
  int id = blockIdx.x;                       // 256 blocks
  int swz = (id & 7) * 32 + (id >> 3);
  const int tm = (swz / 8) * 256, tn = (swz % 8) * 256;
  GEMM256_CORE(A, B)
#pragma unroll
  for (int J = 0; J < 4; ++J) {
    int n = tn + wc * 64 + J * 16 + fr;
#pragma unroll
    for (int I = 0; I < 8; ++I)
#pragma unroll
      for (int rr = 0; rr < 4; ++rr) {
        int m = tm + wr * 128 + I * 16 + fq * 4 + rr;
        C[(size_t)m * 2048 + n] = acc[I][J][rr];
      }
  }
}

// ---------------- flash attention: r8/r11's attn8 verbatim (230us proven) --
__global__ __launch_bounds__(512, 4) void attn8(
    const u16* __restrict__ Q, const u16* __restrict__ K,
    const u16* __restrict__ Vt, u16* __restrict__ Y) {
  __shared__ __align__(16) char smem[49152];
  char* lK = smem;
  char* lV = smem + 16384;
  char* lP = smem + 32768;
  const int tid = threadIdx.x;
  const int lane = tid & 63, w = tid >> 6;
  const int fr = lane & 15, fq = lane >> 4;
  const int pair = blockIdx.x, by = blockIdx.y;
  const size_t hoff = (size_t)pair * 262144;
  const u16* Qh = Q + hoff;
  const u16* Kh = K + hoff;
  const u16* Vth = Vt + hoff;
  const int b = pair >> 4, h = pair & 15;
  const float c1 = 0.08838834764831845f * 1.4426950408889634f;
  const float THR = 11.5f;

  int ksr[2], kcc[2], vdr[2], vcc[2];
#pragma unroll
  for (int it = 0; it < 2; ++it) {
    int idx = it * 512 + tid;
    ksr[it] = idx >> 4; kcc[it] = idx & 15;
    vdr[it] = idx >> 3; vcc[it] = idx & 7;
  }

  for (int phase = 0; phase < 2; ++phase) {
    const int qb = phase ? 15 - by : by;
    const int q0 = qb * 128;
    const int nt = 2 * qb + 2;
    const int qw = q0 + w * 16;

    bf16x8 qf[4];
#pragma unroll
    for (int ks = 0; ks < 4; ++ks)
      qf[ks] = *(const bf16x8*)&Qh[(size_t)(qw + fr) * 128 + ks * 32 + fq * 8];

    f32x4 o[8] = {};
    float m2[4], ls[4];
#pragma unroll
    for (int r = 0; r < 4; ++r) { m2[r] = -1e30f; ls[r] = 0.f; }

    u32x4 kst[2], vst[2];
#pragma unroll
    for (int it = 0; it < 2; ++it) {
      kst[it] = *(const u32x4*)&Kh[(size_t)ksr[it] * 128 + kcc[it] * 8];
      vst[it] = *(const u32x4*)&Vth[(size_t)vdr[it] * 2048 + vcc[it] * 8];
    }

    for (int t = 0; t < nt; ++t) {
      const int kv0 = t * 64;
#pragma unroll
      for (int it = 0; it < 2; ++it) {
        *(u32x4*)(lK + ksr[it] * 256 + ((kcc[it] ^ (ksr[it] & 7)) << 4)) = kst[it];
        *(u32x4*)(lV + vdr[it] * 128 + ((vcc[it] ^ (vdr[it] & 7)) << 4)) = vst[it];
      }
      if (t + 1 < nt) {
        const int nk = kv0 + 64;
#pragma unroll
        for (int it = 0; it < 2; ++it) {
          kst[it] = *(const u32x4*)&Kh[(size_t)(nk + ksr[it]) * 128 + kcc[it] * 8];
          vst[it] = *(const u32x4*)&Vth[(size_t)vdr[it] * 2048 + nk + vcc[it] * 8];
        }
      }
      __syncthreads();

      if (kv0 <= qw + 15) {
        f32x4 sc[4] = {};
#pragma unroll
        for (int j = 0; j < 4; ++j) {
          int s = j * 16 + fr;
#pragma unroll
          for (int ks = 0; ks < 4; ++ks) {
            bf16x8 kf = *(const bf16x8*)(lK + s * 256 + (((ks * 32 + fq * 8) * 2) ^ ((s & 7) << 4)));
            sc[j] = MFMA16(qf[ks], kf, sc[j], 0, 0, 0);
          }
        }
        if (kv0 + 64 > qw) {
          int rowb = qw + fq * 4;
#pragma unroll
          for (int j = 0; j < 4; ++j) {
            int col = kv0 + j * 16 + fr;
#pragma unroll
            for (int r = 0; r < 4; ++r)
              if (col > rowb + r) sc[j][r] = -3e38f;
          }
        }
        float lmax[4];
        bool trip = false;
#pragma unroll
        for (int r = 0; r < 4; ++r) {
          lmax[r] = fmaxf(fmaxf(sc[0][r], sc[1][r]), fmaxf(sc[2][r], sc[3][r]));
          trip = trip || (lmax[r] * c1 > m2[r] + THR);
        }
        if (__any(trip)) {
#pragma unroll
          for (int r = 0; r < 4; ++r) {
            float v = lmax[r];
            v = fmaxf(v, __shfl_xor(v, 1));
            v = fmaxf(v, __shfl_xor(v, 2));
            v = fmaxf(v, __shfl_xor(v, 4));
            v = fmaxf(v, __shfl_xor(v, 8));
            v *= c1;
            float mn = fmaxf(m2[r], v);
            float corr = __builtin_amdgcn_exp2f(m2[r] - mn);
            m2[r] = mn;
            ls[r] *= corr;
#pragma unroll
            for (int n = 0; n < 8; ++n) o[n][r] *= corr;
          }
        }
#pragma unroll
        for (int r = 0; r < 4; ++r) {
          int prow = w * 16 + fq * 4 + r;
          float rs = 0.f;
#pragma unroll
          for (int j = 0; j < 4; ++j) {
            float p = __builtin_amdgcn_exp2f(sc[j][r] * c1 - m2[r]);
            rs += p;
            *(u16*)(lP + prow * 128 + (((j * 16 + fr) * 2) ^ ((prow & 7) << 4))) = f2bf(p);
          }
          ls[r] += rs;
        }
        bf16x8 pf[2];
        {
          int prow = w * 16 + fr;
#pragma unroll
          for (int k2 = 0; k2 < 2; ++k2)
            pf[k2] = *(const bf16x8*)(lP + prow * 128 + ((k2 * 64 + fq * 16) ^ ((prow & 7) << 4)));
        }
#pragma unroll
        for (int n = 0; n < 8; ++n) {
          int d = n * 16 + fr;
#pragma unroll
          for (int k2 = 0; k2 < 2; ++k2) {
            bf16x8 vf = *(const bf16x8*)(lV + d * 128 + ((k2 * 64 + fq * 16) ^ ((d & 7) << 4)));
            o[n] = MFMA16(pf[k2], vf, o[n], 0, 0, 0);
          }
        }
      }
      __syncthreads();
    }

    float inv[4];
#pragma unroll
    for (int r = 0; r < 4; ++r) {
      float s = ls[r];
      s += __shfl_xor(s, 1);
      s += __shfl_xor(s, 2);
      s += __shfl_xor(s, 4);
      s += __shfl_xor(s, 8);
      inv[r] = 1.f / s;
    }
#pragma unroll
    for (int n = 0; n < 8; ++n)
#pragma unroll
      for (int r = 0; r < 4; ++r) {
        int tt = qw + fq * 4 + r;
        Y[((size_t)(b * 2048 + tt) * 2048) + h * 128 + n * 16 + fr] = f2bf(o[n][r] * inv[r]);
      }
  }
}

// ---------------------------------------------------------------------------
extern "C" void kernel_launch(void* const* d_in, const int* in_sizes, int n_in,
                              void* d_out, int out_size, void* d_ws, size_t ws_size,
                              hipStream_t stream) {
  const float* x = (const float*)d_in[0];
  const float* Win = (const float*)d_in[1];
  const float* Wout = (const float*)d_in[2];
  float* out = (float*)d_out;
  char* ws = (char*)d_ws;

  u16* x_bf   = (u16*)(ws);                  // 33554432 B
  u16* win_bf = (u16*)(ws + 33554432);       // 25165824 B
  u16* wout_bf= (u16*)(ws + 58720256);       //  8388608 B
  u16* Qb     = (u16*)(ws + 67108864);       // 33554432 B
  u16* Kb     = (u16*)(ws + 100663296);      // 33554432 B
  u16* Vtb    = (u16*)(ws + 134217728);      // 33554432 B (V^T, fused epilogue)
  u16* y_bf   = (u16*)(ws + 167772160);      // 33554432 B  (total 192 MiB)

  convert_bf16<<<2048, 256, 0, stream>>>(x, x_bf, 16777216 / 4);
  convert_bf16<<<2048, 256, 0, stream>>>(Win, win_bf, 12582912 / 4);
  convert_bf16<<<1024, 256, 0, stream>>>(Wout, wout_bf, 4194304 / 4);

  gemm_qkv8<<<768, 512, 0, stream>>>(x_bf, win_bf, Qb, Kb, Vtb);
  attn8<<<dim3(64, 8), 512, 0, stream>>>(Qb, Kb, Vtb, y_bf);
  gemm_out8<<<256, 512, 0, stream>>>(y_bf, wout_bf, out);
}